// Round 1
// baseline (1720.440 us; speedup 1.0000x reference)
//
#include <hip/hip_runtime.h>
#include <hip/hip_bf16.h>

#define NB   2048   // batch
#define NG   2000   // genes
#define NC   50     // concepts
#define NH   256    // hidden
#define NZD  32     // latent
#define NK   10     // prototypes (classes)
#define NP   4      // per-class prototypes
#define BT   64     // batch tile
#define GSTRIDE 2048

// ---------------- kernel 1: deterministic ordered compaction of M ----------
__global__ void build_gidx(const float* __restrict__ M, int* __restrict__ gidx,
                           int* __restrict__ gcnt) {
    int c = blockIdx.x;
    int t = threadIdx.x;
    __shared__ int wcnt[4];
    __shared__ int base;
    if (t == 0) base = 0;
    __syncthreads();
    for (int g0 = 0; g0 < NG; g0 += 256) {
        int g = g0 + t;
        bool a = (g < NG) && (M[c * NG + g] != 0.0f);
        unsigned long long mask = __ballot(a);
        int lane = t & 63;
        int w = t >> 6;
        if (lane == 0) wcnt[w] = __popcll(mask);
        int pre = __popcll(mask & ((1ull << lane) - 1ull));
        __syncthreads();
        int woff = base;
        for (int i = 0; i < w; ++i) woff += wcnt[i];
        if (a) gidx[c * GSTRIDE + woff + pre] = g;
        int tot = wcnt[0] + wcnt[1] + wcnt[2] + wcnt[3];
        __syncthreads();
        if (t == 0) base += tot;
        __syncthreads();
    }
    if (t == 0) gcnt[c] = base;
}

// ---------------- kernel 2: fused encoder + heads + prototype distances ----
// grid (NB/BT, NC), 256 threads.
// LDS: sh_big[64][258] (h1/h2), sh_w[32][258] (W1/W2 chunk, cw, protos),
//      sh_x[64][33] (gathered X chunk, then Z), sh_gid[32].
__global__ __launch_bounds__(256, 1) void fused_main(
    const float* __restrict__ X,  const float* __restrict__ W1,
    const float* __restrict__ b1, const float* __restrict__ W2,
    const float* __restrict__ b2, const float* __restrict__ cw,
    const float* __restrict__ cb, const float* __restrict__ protos,
    const float* __restrict__ logvar, const float* __restrict__ c_bias,
    const int* __restrict__ gidx, const int* __restrict__ gcnt,
    float* __restrict__ out_cl)
{
    extern __shared__ float smemf[];
    float (*sh_big)[258] = (float (*)[258])smemf;                 // 16512 f
    float (*sh_w)[258]   = (float (*)[258])(smemf + 16512);       //  8256 f
    float (*sh_x)[33]    = (float (*)[33])(smemf + 16512 + 8256); //  2112 f
    int*  sh_gid         = (int*)(smemf + 16512 + 8256 + 2112);   //    32 i

    const int t   = threadIdx.x;
    const int tx  = t & 15;
    const int ty  = t >> 4;            // 0..15
    const int row0 = blockIdx.x * BT;
    const int c    = blockIdx.y;

    // ---------------- stage A: h1 = leaky(Xc @ W1c + b1), sparse genes ------
    float acc[4][16];
    #pragma unroll
    for (int i = 0; i < 4; ++i)
        #pragma unroll
        for (int l = 0; l < 16; ++l) acc[i][l] = 0.f;

    const int cnt = gcnt[c];
    const int nch = (cnt + 31) >> 5;
    for (int ch = 0; ch < nch; ++ch) {
        __syncthreads();
        if (t < 32) {
            int gi = ch * 32 + t;
            sh_gid[t] = (gi < cnt) ? gidx[c * GSTRIDE + gi] : -1;
        }
        __syncthreads();
        #pragma unroll 4
        for (int jj = 0; jj < 32; ++jj) {           // W1 rows, coalesced
            int g = sh_gid[jj];
            sh_w[jj][t] = (g >= 0) ? W1[g * NH + t] : 0.f;
        }
        {
            int j  = t & 31;
            int rb = (t >> 5) * 8;
            int g  = sh_gid[j];
            #pragma unroll
            for (int ii = 0; ii < 8; ++ii)          // gathered X
                sh_x[rb + ii][j] = (g >= 0) ? X[(size_t)(row0 + rb + ii) * NG + g] : 0.f;
        }
        __syncthreads();
        #pragma unroll 8
        for (int j = 0; j < 32; ++j) {
            float xv[4];
            #pragma unroll
            for (int i = 0; i < 4; ++i) xv[i] = sh_x[ty * 4 + i][j];
            #pragma unroll
            for (int l = 0; l < 16; ++l) {
                float wv = sh_w[j][l * 16 + tx];
                #pragma unroll
                for (int i = 0; i < 4; ++i) acc[i][l] = fmaf(xv[i], wv, acc[i][l]);
            }
        }
    }

    // h1 -> sh_big (bias + leaky_relu 0.01)
    #pragma unroll
    for (int i = 0; i < 4; ++i)
        #pragma unroll
        for (int l = 0; l < 16; ++l) {
            int col = l * 16 + tx;
            float v = acc[i][l] + b1[col];
            sh_big[ty * 4 + i][col] = (v >= 0.f) ? v : 0.01f * v;
        }

    // ---------------- stage B: h2 = leaky(h1 @ W2 + b2) ---------------------
    float acc2[4][16];
    #pragma unroll
    for (int i = 0; i < 4; ++i)
        #pragma unroll
        for (int l = 0; l < 16; ++l) acc2[i][l] = 0.f;

    for (int ch = 0; ch < NH / 32; ++ch) {
        __syncthreads();
        #pragma unroll 4
        for (int jj = 0; jj < 32; ++jj)
            sh_w[jj][t] = W2[(ch * 32 + jj) * NH + t];
        __syncthreads();
        #pragma unroll 8
        for (int j = 0; j < 32; ++j) {
            float xv[4];
            #pragma unroll
            for (int i = 0; i < 4; ++i) xv[i] = sh_big[ty * 4 + i][ch * 32 + j];
            #pragma unroll
            for (int l = 0; l < 16; ++l) {
                float wv = sh_w[j][l * 16 + tx];
                #pragma unroll
                for (int i = 0; i < 4; ++i) acc2[i][l] = fmaf(xv[i], wv, acc2[i][l]);
            }
        }
    }

    __syncthreads();
    // h2 -> sh_big; stage cw -> sh_w
    #pragma unroll
    for (int i = 0; i < 4; ++i)
        #pragma unroll
        for (int l = 0; l < 16; ++l) {
            int col = l * 16 + tx;
            float v = acc2[i][l] + b2[col];
            sh_big[ty * 4 + i][col] = (v >= 0.f) ? v : 0.01f * v;
        }
    #pragma unroll 4
    for (int o = 0; o < NZD; ++o)
        sh_w[o][t] = cw[((size_t)c * NZD + o) * NH + t];
    __syncthreads();

    // ---------------- stage C: Z = h2 @ cw^T + cb ---------------------------
    {
        int o  = t & 31;
        int rg = t >> 5;                    // 0..7
        float cbv = cb[c * NZD + o];
        float zv[8];
        #pragma unroll
        for (int i = 0; i < 8; ++i) zv[i] = cbv;
        for (int h = 0; h < NH; ++h) {
            float wv = sh_w[o][h];
            #pragma unroll
            for (int i = 0; i < 8; ++i)
                zv[i] = fmaf(sh_big[rg * 8 + i][h], wv, zv[i]);
        }
        #pragma unroll
        for (int i = 0; i < 8; ++i) sh_x[rg * 8 + i][o] = zv[i];  // Zs
    }
    __syncthreads();

    // ---------------- stage D: prototype distances -> c_logits --------------
    float* proto_s = &sh_w[0][0];          // 1280 floats
    float* i2e_s   = proto_s + NK * NP * NZD;
    float* cbias_s = i2e_s + NK * NP;
    for (int i = t; i < NK * NP * NZD; i += 256)
        proto_s[i] = protos[(size_t)c * NK * NP * NZD + i];
    if (t < NK * NP) i2e_s[t] = 0.5f * expf(-logvar[c * NK * NP + t]);
    if (t < NK)      cbias_s[t] = c_bias[c * NK + t];
    __syncthreads();

    for (int task = t; task < BT * NK; task += 256) {
        int r = task / NK;
        int k = task - r * NK;
        float best = 3.4e38f;
        #pragma unroll
        for (int p = 0; p < NP; ++p) {
            float d2 = 0.f;
            const float* pp = proto_s + (k * NP + p) * NZD;
            #pragma unroll
            for (int o = 0; o < NZD; ++o) {
                float dv = sh_x[r][o] - pp[o];
                d2 = fmaf(dv, dv, d2);
            }
            float sc = d2 * i2e_s[k * NP + p];
            best = fminf(best, sc);
        }
        out_cl[((size_t)(row0 + r) * NC + c) * NK + k] = cbias_s[k] - best;
    }
}

// ---------------- kernel 3: logits = log(sum_c exp(cl)*|imp| + 1e-16) + bias
__global__ void reduce_logits(const float* __restrict__ cl,
                              const float* __restrict__ importance,
                              const float* __restrict__ bias,
                              float* __restrict__ out) {
    int idx = blockIdx.x * blockDim.x + threadIdx.x;
    if (idx >= NB * NK) return;
    int b = idx / NK;
    int k = idx - b * NK;
    float s = 0.f;
    for (int c = 0; c < NC; ++c) {
        float imp = fabsf(importance[c]);
        s += expf(cl[((size_t)b * NC + c) * NK + k]) * imp + 1e-16f;
    }
    out[idx] = logf(s) + bias[k];
}

extern "C" void kernel_launch(void* const* d_in, const int* in_sizes, int n_in,
                              void* d_out, int out_size, void* d_ws, size_t ws_size,
                              hipStream_t stream) {
    const float* X      = (const float*)d_in[0];
    const float* M      = (const float*)d_in[1];
    const float* W1     = (const float*)d_in[2];
    const float* b1     = (const float*)d_in[3];
    const float* W2     = (const float*)d_in[4];
    const float* b2     = (const float*)d_in[5];
    const float* cw     = (const float*)d_in[6];
    const float* cb     = (const float*)d_in[7];
    const float* protos = (const float*)d_in[8];
    const float* logvar = (const float*)d_in[9];
    const float* c_bias = (const float*)d_in[10];
    const float* bias   = (const float*)d_in[11];
    const float* imp    = (const float*)d_in[12];

    float* out_logits = (float*)d_out;           // [B, K]
    float* out_cl     = out_logits + NB * NK;    // [B, C, K]

    int* gidx = (int*)d_ws;                      // [C, 2048]
    int* gcnt = gidx + NC * GSTRIDE;             // [C]

    build_gidx<<<NC, 256, 0, stream>>>(M, gidx, gcnt);

    size_t smem = (size_t)(16512 + 8256 + 2112) * 4 + 32 * 4;  // 107776 B
    fused_main<<<dim3(NB / BT, NC), 256, smem, stream>>>(
        X, W1, b1, W2, b2, cw, cb, protos, logvar, c_bias, gidx, gcnt, out_cl);

    reduce_logits<<<(NB * NK + 255) / 256, 256, 0, stream>>>(out_cl, imp, bias, out_logits);
}

// Round 2
// 209.561 us; speedup vs baseline: 8.2097x; 8.2097x over previous
//
#include <hip/hip_runtime.h>
#include <hip/hip_bf16.h>

#define NB   2048
#define NG   2000
#define NC   50
#define NH   256
#define NZD  32
#define NK   10
#define NP   4
#define BT   64
#define GS   2048
#define KP   320    // padded per-concept gene count (cnt ~200, P(cnt>320)~0)

typedef short short8 __attribute__((ext_vector_type(8)));
typedef float f32x4  __attribute__((ext_vector_type(4)));

__device__ __forceinline__ unsigned short f2bf(float f) {
    union { float f; unsigned u; } v; v.f = f;
    unsigned r = v.u + 0x7fffu + ((v.u >> 16) & 1u);
    return (unsigned short)(r >> 16);
}

// ---------------- kernel: deterministic ordered compaction of M ------------
__global__ void build_gidx(const float* __restrict__ M, int* __restrict__ gidx,
                           int* __restrict__ gcnt) {
    int c = blockIdx.x;
    int t = threadIdx.x;
    __shared__ int wcnt[4];
    __shared__ int base;
    if (t == 0) base = 0;
    __syncthreads();
    for (int g0 = 0; g0 < NG; g0 += 256) {
        int g = g0 + t;
        bool a = (g < NG) && (M[c * NG + g] != 0.0f);
        unsigned long long mask = __ballot(a);
        int lane = t & 63;
        int w = t >> 6;
        if (lane == 0) wcnt[w] = __popcll(mask);
        int pre = __popcll(mask & ((1ull << lane) - 1ull));
        __syncthreads();
        int woff = base;
        for (int i = 0; i < w; ++i) woff += wcnt[i];
        if (a) gidx[c * GS + woff + pre] = g;
        int tot = wcnt[0] + wcnt[1] + wcnt[2] + wcnt[3];
        __syncthreads();
        if (t == 0) base += tot;
        __syncthreads();
    }
    if (t == 0) gcnt[c] = base;
}

// ---------------- prep kernels (bf16 transposed weight caches) -------------
__global__ void prep_w1c(const float* __restrict__ W1, const int* __restrict__ gidx,
                         const int* __restrict__ gcnt, unsigned short* __restrict__ w1c) {
    int c   = blockIdx.y;
    int col = blockIdx.x * 8 + (threadIdx.x >> 5);
    int kin = threadIdx.x & 31;
    int cnt = gcnt[c]; if (cnt > KP) cnt = KP;
    for (int kc = 0; kc < KP / 32; ++kc) {
        int k = kc * 32 + kin;
        int g = (k < cnt) ? gidx[c * GS + k] : -1;
        unsigned short v = 0;
        if (g >= 0) v = f2bf(W1[(size_t)g * NH + col]);
        w1c[(size_t)(c * NH + col) * KP + k] = v;
    }
}

__global__ void prep_w2t(const float* __restrict__ W2, unsigned short* __restrict__ w2t) {
    int col = blockIdx.x, h = threadIdx.x;
    w2t[(size_t)col * NH + h] = f2bf(W2[(size_t)h * NH + col]);
}

__global__ void prep_cwb(const float* __restrict__ cw, unsigned short* __restrict__ cwb) {
    int i = blockIdx.x * 256 + threadIdx.x;
    if (i < NC * NZD * NH) cwb[i] = f2bf(cw[i]);
}

// ---------------- main fused kernel (bf16 MFMA) ----------------------------
// grid (NB/BT, NC), 256 threads = 4 waves. Per wave: 64 rows x 64 cols.
#define H_BASE   0        // bf16 [64][256] swizzled  (32768 B)
#define SW_BASE  32768    // bf16 [256][32] / SCW [32][256] swz (16384 B)
#define SX_BASE  49152    // bf16 [64][32] / stage-D protos (5440 B)
#define SZ_BASE  54592    // f32 [64][33]  (8448 B)
#define LDS_BYTES 63040

__global__ __launch_bounds__(256, 2) void fused_mfma(
    const float* __restrict__ X,  const float* __restrict__ b1,
    const float* __restrict__ b2, const float* __restrict__ cb,
    const float* __restrict__ protos, const float* __restrict__ logvar,
    const float* __restrict__ c_bias,
    const unsigned short* __restrict__ w1c, const unsigned short* __restrict__ w2t,
    const unsigned short* __restrict__ cwb,
    const int* __restrict__ gidx, const int* __restrict__ gcnt,
    float* __restrict__ out_cl)
{
    extern __shared__ char sm[];
    const int t  = threadIdx.x;
    const int l  = t & 63;
    const int w  = t >> 6;
    const int lr = l & 15;    // row/col within 16x16 subtile
    const int lg = l >> 4;    // k-group 0..3
    const int row0 = blockIdx.x * BT;
    const int c    = blockIdx.y;
    int cnt = gcnt[c]; if (cnt > KP) cnt = KP;
    const int nch = (cnt + 31) >> 5;

    auto Hb = [&](int r, int k) -> char* {   // swizzled [64][256] bf16
        return sm + H_BASE + r * 512 + ((((k >> 3) ^ (r & 7)) << 4) | ((k & 7) << 1));
    };
    auto SWb = [&](int col, int k) -> char* { return sm + SW_BASE + col * 64 + (k << 1); };
    auto SXb = [&](int r, int k) -> char* { return sm + SX_BASE + r * 64 + (k << 1); };
    auto SCWb = [&](int o, int k) -> char* { // swizzled [32][256] bf16
        return sm + SW_BASE + o * 512 + ((((k >> 3) ^ (o & 7)) << 4) | ((k & 7) << 1));
    };
    float (*SZ)[33] = (float (*)[33])(sm + SZ_BASE);

    f32x4 acc[4][4];
    #pragma unroll
    for (int m = 0; m < 4; ++m)
        #pragma unroll
        for (int n = 0; n < 4; ++n) acc[m][n] = f32x4{0.f, 0.f, 0.f, 0.f};

    // ---------------- stage A: h1 = leaky(Xc @ W1c + b1) --------------------
    {
        const int j = t & 31, rg = t >> 5;   // SX staging: gene j, row group
        const int q = t & 3,  colb = t >> 2; // SW staging
        for (int ch = 0; ch < nch; ++ch) {
            const int kb = ch * 32;
            __syncthreads();
            int g = (kb + j < cnt) ? gidx[c * GS + kb + j] : -1;
            #pragma unroll
            for (int ii = 0; ii < 8; ++ii) {
                float xv = (g >= 0) ? X[(size_t)(row0 + rg * 8 + ii) * NG + g] : 0.f;
                *(unsigned short*)SXb(rg * 8 + ii, j) = f2bf(xv);
            }
            #pragma unroll
            for (int it = 0; it < 4; ++it) {
                int col = colb + it * 64;
                short8 v = *(const short8*)(w1c + ((size_t)(c * NH + col) * KP + kb + q * 8));
                *(short8*)SWb(col, q * 8) = v;
            }
            __syncthreads();
            short8 am[4], bn[4];
            #pragma unroll
            for (int m = 0; m < 4; ++m) am[m] = *(const short8*)SXb(m * 16 + lr, lg * 8);
            #pragma unroll
            for (int n = 0; n < 4; ++n) bn[n] = *(const short8*)SWb(w * 64 + n * 16 + lr, lg * 8);
            #pragma unroll
            for (int m = 0; m < 4; ++m)
                #pragma unroll
                for (int n = 0; n < 4; ++n)
                    acc[m][n] = __builtin_amdgcn_mfma_f32_16x16x32_bf16(am[m], bn[n], acc[m][n], 0, 0, 0);
        }
    }
    // epilogue A: bias + leaky -> H (bf16)
    #pragma unroll
    for (int n = 0; n < 4; ++n) {
        int col = w * 64 + n * 16 + lr;
        float bv = b1[col];
        #pragma unroll
        for (int m = 0; m < 4; ++m)
            #pragma unroll
            for (int i = 0; i < 4; ++i) {
                int row = m * 16 + lg * 4 + i;
                float v = acc[m][n][i] + bv;
                v = (v >= 0.f) ? v : 0.01f * v;
                *(unsigned short*)Hb(row, col) = f2bf(v);
            }
    }

    // ---------------- stage B: h2 = leaky(h1 @ W2 + b2) ---------------------
    #pragma unroll
    for (int m = 0; m < 4; ++m)
        #pragma unroll
        for (int n = 0; n < 4; ++n) acc[m][n] = f32x4{0.f, 0.f, 0.f, 0.f};
    {
        const int q = t & 3, colb = t >> 2;
        for (int ch = 0; ch < 8; ++ch) {
            const int kb = ch * 32;
            __syncthreads();
            #pragma unroll
            for (int it = 0; it < 4; ++it) {
                int col = colb + it * 64;
                short8 v = *(const short8*)(w2t + ((size_t)col * NH + kb + q * 8));
                *(short8*)SWb(col, q * 8) = v;
            }
            __syncthreads();
            short8 am[4], bn[4];
            #pragma unroll
            for (int m = 0; m < 4; ++m) am[m] = *(const short8*)Hb(m * 16 + lr, kb + lg * 8);
            #pragma unroll
            for (int n = 0; n < 4; ++n) bn[n] = *(const short8*)SWb(w * 64 + n * 16 + lr, lg * 8);
            #pragma unroll
            for (int m = 0; m < 4; ++m)
                #pragma unroll
                for (int n = 0; n < 4; ++n)
                    acc[m][n] = __builtin_amdgcn_mfma_f32_16x16x32_bf16(am[m], bn[n], acc[m][n], 0, 0, 0);
        }
    }
    __syncthreads();   // all H(h1) + SW reads done
    // epilogue B: h2 -> H (overwrite)
    #pragma unroll
    for (int n = 0; n < 4; ++n) {
        int col = w * 64 + n * 16 + lr;
        float bv = b2[col];
        #pragma unroll
        for (int m = 0; m < 4; ++m)
            #pragma unroll
            for (int i = 0; i < 4; ++i) {
                int row = m * 16 + lg * 4 + i;
                float v = acc[m][n][i] + bv;
                v = (v >= 0.f) ? v : 0.01f * v;
                *(unsigned short*)Hb(row, col) = f2bf(v);
            }
    }
    // stage C staging: cw -> SCW, protos -> SX region
    {
        int o = t >> 3, q8 = t & 7;
        #pragma unroll
        for (int p = 0; p < 4; ++p) {
            int k = q8 * 8 + p * 64;
            short8 v = *(const short8*)(cwb + ((size_t)(c * NZD + o) * NH + k));
            *(short8*)SCWb(o, k) = v;
        }
        float* proto_s = (float*)(sm + SX_BASE);
        float* i2e_s   = proto_s + NK * NP * NZD;
        float* cbias_s = i2e_s + NK * NP;
        for (int i = t; i < NK * NP * NZD; i += 256)
            proto_s[i] = protos[(size_t)c * NK * NP * NZD + i];
        if (t < NK * NP) i2e_s[t] = 0.5f * expf(-logvar[c * NK * NP + t]);
        if (t < NK)      cbias_s[t] = c_bias[c * NK + t];
    }
    __syncthreads();

    // ---------------- stage C: Z = h2 @ cw^T + cb (rows w*16..+15) ----------
    {
        f32x4 az[2];
        az[0] = f32x4{0.f, 0.f, 0.f, 0.f};
        az[1] = f32x4{0.f, 0.f, 0.f, 0.f};
        for (int ch = 0; ch < 8; ++ch) {
            int kb = ch * 32;
            short8 am = *(const short8*)Hb(w * 16 + lr, kb + lg * 8);
            #pragma unroll
            for (int n = 0; n < 2; ++n) {
                short8 bo = *(const short8*)SCWb(n * 16 + lr, kb + lg * 8);
                az[n] = __builtin_amdgcn_mfma_f32_16x16x32_bf16(am, bo, az[n], 0, 0, 0);
            }
        }
        #pragma unroll
        for (int n = 0; n < 2; ++n)
            #pragma unroll
            for (int i = 0; i < 4; ++i) {
                int row = w * 16 + lg * 4 + i;
                int o   = n * 16 + lr;
                SZ[row][o] = az[n][i] + cb[c * NZD + o];
            }
    }
    __syncthreads();

    // ---------------- stage D: prototype distances -> c_logits --------------
    {
        float* proto_s = (float*)(sm + SX_BASE);
        float* i2e_s   = proto_s + NK * NP * NZD;
        float* cbias_s = i2e_s + NK * NP;
        for (int task = t; task < BT * NK; task += 256) {
            int r = task / NK;
            int k = task - r * NK;
            float best = 3.4e38f;
            #pragma unroll
            for (int p = 0; p < NP; ++p) {
                float d2 = 0.f;
                const float* pp = proto_s + (k * NP + p) * NZD;
                #pragma unroll
                for (int o = 0; o < NZD; ++o) {
                    float dv = SZ[r][o] - pp[o];
                    d2 = fmaf(dv, dv, d2);
                }
                float sc = d2 * i2e_s[k * NP + p];
                best = fminf(best, sc);
            }
            out_cl[((size_t)(row0 + r) * NC + c) * NK + k] = cbias_s[k] - best;
        }
    }
}

// ---------------- fallback (round-1 fp32 path, known-good) -----------------
__global__ __launch_bounds__(256, 1) void fused_main(
    const float* __restrict__ X,  const float* __restrict__ W1,
    const float* __restrict__ b1, const float* __restrict__ W2,
    const float* __restrict__ b2, const float* __restrict__ cw,
    const float* __restrict__ cb, const float* __restrict__ protos,
    const float* __restrict__ logvar, const float* __restrict__ c_bias,
    const int* __restrict__ gidx, const int* __restrict__ gcnt,
    float* __restrict__ out_cl)
{
    extern __shared__ float smemf[];
    float (*sh_big)[258] = (float (*)[258])smemf;
    float (*sh_w)[258]   = (float (*)[258])(smemf + 16512);
    float (*sh_x)[33]    = (float (*)[33])(smemf + 16512 + 8256);
    int*  sh_gid         = (int*)(smemf + 16512 + 8256 + 2112);

    const int t   = threadIdx.x;
    const int tx  = t & 15;
    const int ty  = t >> 4;
    const int row0 = blockIdx.x * BT;
    const int c    = blockIdx.y;

    float acc[4][16];
    #pragma unroll
    for (int i = 0; i < 4; ++i)
        #pragma unroll
        for (int l = 0; l < 16; ++l) acc[i][l] = 0.f;

    const int cnt = gcnt[c];
    const int nch = (cnt + 31) >> 5;
    for (int ch = 0; ch < nch; ++ch) {
        __syncthreads();
        if (t < 32) {
            int gi = ch * 32 + t;
            sh_gid[t] = (gi < cnt) ? gidx[c * GS + gi] : -1;
        }
        __syncthreads();
        #pragma unroll 4
        for (int jj = 0; jj < 32; ++jj) {
            int g = sh_gid[jj];
            sh_w[jj][t] = (g >= 0) ? W1[g * NH + t] : 0.f;
        }
        {
            int j  = t & 31;
            int rb = (t >> 5) * 8;
            int g  = sh_gid[j];
            #pragma unroll
            for (int ii = 0; ii < 8; ++ii)
                sh_x[rb + ii][j] = (g >= 0) ? X[(size_t)(row0 + rb + ii) * NG + g] : 0.f;
        }
        __syncthreads();
        #pragma unroll 8
        for (int j = 0; j < 32; ++j) {
            float xv[4];
            #pragma unroll
            for (int i = 0; i < 4; ++i) xv[i] = sh_x[ty * 4 + i][j];
            #pragma unroll
            for (int l = 0; l < 16; ++l) {
                float wv = sh_w[j][l * 16 + tx];
                #pragma unroll
                for (int i = 0; i < 4; ++i) acc[i][l] = fmaf(xv[i], wv, acc[i][l]);
            }
        }
    }
    #pragma unroll
    for (int i = 0; i < 4; ++i)
        #pragma unroll
        for (int l = 0; l < 16; ++l) {
            int col = l * 16 + tx;
            float v = acc[i][l] + b1[col];
            sh_big[ty * 4 + i][col] = (v >= 0.f) ? v : 0.01f * v;
        }

    float acc2[4][16];
    #pragma unroll
    for (int i = 0; i < 4; ++i)
        #pragma unroll
        for (int l = 0; l < 16; ++l) acc2[i][l] = 0.f;
    for (int ch = 0; ch < NH / 32; ++ch) {
        __syncthreads();
        #pragma unroll 4
        for (int jj = 0; jj < 32; ++jj)
            sh_w[jj][t] = W2[(ch * 32 + jj) * NH + t];
        __syncthreads();
        #pragma unroll 8
        for (int j = 0; j < 32; ++j) {
            float xv[4];
            #pragma unroll
            for (int i = 0; i < 4; ++i) xv[i] = sh_big[ty * 4 + i][ch * 32 + j];
            #pragma unroll
            for (int l = 0; l < 16; ++l) {
                float wv = sh_w[j][l * 16 + tx];
                #pragma unroll
                for (int i = 0; i < 4; ++i) acc2[i][l] = fmaf(xv[i], wv, acc2[i][l]);
            }
        }
    }
    __syncthreads();
    #pragma unroll
    for (int i = 0; i < 4; ++i)
        #pragma unroll
        for (int l = 0; l < 16; ++l) {
            int col = l * 16 + tx;
            float v = acc2[i][l] + b2[col];
            sh_big[ty * 4 + i][col] = (v >= 0.f) ? v : 0.01f * v;
        }
    #pragma unroll 4
    for (int o = 0; o < NZD; ++o)
        sh_w[o][t] = cw[((size_t)c * NZD + o) * NH + t];
    __syncthreads();
    {
        int o  = t & 31;
        int rg = t >> 5;
        float cbv = cb[c * NZD + o];
        float zv[8];
        #pragma unroll
        for (int i = 0; i < 8; ++i) zv[i] = cbv;
        for (int h = 0; h < NH; ++h) {
            float wv = sh_w[o][h];
            #pragma unroll
            for (int i = 0; i < 8; ++i)
                zv[i] = fmaf(sh_big[rg * 8 + i][h], wv, zv[i]);
        }
        #pragma unroll
        for (int i = 0; i < 8; ++i) sh_x[rg * 8 + i][o] = zv[i];
    }
    __syncthreads();
    float* proto_s = &sh_w[0][0];
    float* i2e_s   = proto_s + NK * NP * NZD;
    float* cbias_s = i2e_s + NK * NP;
    for (int i = t; i < NK * NP * NZD; i += 256)
        proto_s[i] = protos[(size_t)c * NK * NP * NZD + i];
    if (t < NK * NP) i2e_s[t] = 0.5f * expf(-logvar[c * NK * NP + t]);
    if (t < NK)      cbias_s[t] = c_bias[c * NK + t];
    __syncthreads();
    for (int task = t; task < BT * NK; task += 256) {
        int r = task / NK;
        int k = task - r * NK;
        float best = 3.4e38f;
        #pragma unroll
        for (int p = 0; p < NP; ++p) {
            float d2 = 0.f;
            const float* pp = proto_s + (k * NP + p) * NZD;
            #pragma unroll
            for (int o = 0; o < NZD; ++o) {
                float dv = sh_x[r][o] - pp[o];
                d2 = fmaf(dv, dv, d2);
            }
            float sc = d2 * i2e_s[k * NP + p];
            best = fminf(best, sc);
        }
        out_cl[((size_t)(row0 + r) * NC + c) * NK + k] = cbias_s[k] - best;
    }
}

// ---------------- logits reduce --------------------------------------------
__global__ void reduce_logits(const float* __restrict__ cl,
                              const float* __restrict__ importance,
                              const float* __restrict__ bias,
                              float* __restrict__ out) {
    int idx = blockIdx.x * blockDim.x + threadIdx.x;
    if (idx >= NB * NK) return;
    int b = idx / NK;
    int k = idx - b * NK;
    float s = 0.f;
    for (int c = 0; c < NC; ++c) {
        float imp = fabsf(importance[c]);
        s += expf(cl[((size_t)b * NC + c) * NK + k]) * imp + 1e-16f;
    }
    out[idx] = logf(s) + bias[k];
}

extern "C" void kernel_launch(void* const* d_in, const int* in_sizes, int n_in,
                              void* d_out, int out_size, void* d_ws, size_t ws_size,
                              hipStream_t stream) {
    const float* X      = (const float*)d_in[0];
    const float* M      = (const float*)d_in[1];
    const float* W1     = (const float*)d_in[2];
    const float* b1     = (const float*)d_in[3];
    const float* W2     = (const float*)d_in[4];
    const float* b2     = (const float*)d_in[5];
    const float* cw     = (const float*)d_in[6];
    const float* cb     = (const float*)d_in[7];
    const float* protos = (const float*)d_in[8];
    const float* logvar = (const float*)d_in[9];
    const float* c_bias = (const float*)d_in[10];
    const float* bias   = (const float*)d_in[11];
    const float* imp    = (const float*)d_in[12];

    float* out_logits = (float*)d_out;
    float* out_cl     = out_logits + NB * NK;

    int* gidx = (int*)d_ws;
    int* gcnt = gidx + NC * GS;
    size_t off1 = (size_t)NC * GS * 4 + 256;                 // w1c
    size_t off2 = off1 + (size_t)NC * NH * KP * 2;           // w2t
    size_t off3 = off2 + (size_t)NH * NH * 2;                // cwb
    size_t need = off3 + (size_t)NC * NZD * NH * 2;
    unsigned short* w1c = (unsigned short*)((char*)d_ws + off1);
    unsigned short* w2t = (unsigned short*)((char*)d_ws + off2);
    unsigned short* cwb = (unsigned short*)((char*)d_ws + off3);

    build_gidx<<<NC, 256, 0, stream>>>(M, gidx, gcnt);

    if (ws_size >= need) {
        prep_w1c<<<dim3(32, NC), 256, 0, stream>>>(W1, gidx, gcnt, w1c);
        prep_w2t<<<NH, NH, 0, stream>>>(W2, w2t);
        prep_cwb<<<(NC * NZD * NH + 255) / 256, 256, 0, stream>>>(cw, cwb);
        fused_mfma<<<dim3(NB / BT, NC), 256, LDS_BYTES, stream>>>(
            X, b1, b2, cb, protos, logvar, c_bias, w1c, w2t, cwb, gidx, gcnt, out_cl);
    } else {
        size_t smem = (size_t)(16512 + 8256 + 2112) * 4 + 32 * 4;
        fused_main<<<dim3(NB / BT, NC), 256, smem, stream>>>(
            X, W1, b1, W2, b2, cw, cb, protos, logvar, c_bias, gidx, gcnt, out_cl);
    }
    reduce_logits<<<(NB * NK + 255) / 256, 256, 0, stream>>>(out_cl, imp, bias, out_logits);
}

// Round 3
// 119.313 us; speedup vs baseline: 14.4195x; 1.7564x over previous
//
#include <hip/hip_runtime.h>
#include <hip/hip_bf16.h>

#define NB   2048
#define NG   2000
#define NC   50
#define NH   256
#define NZD  32
#define NK   10
#define NP   4
#define BT   64
#define GS   2048
#define KP   320
#define NCH  10      // KP/32

typedef short short8  __attribute__((ext_vector_type(8)));
typedef short short4v __attribute__((ext_vector_type(4)));
typedef float f32x4   __attribute__((ext_vector_type(4)));
typedef unsigned int uint2v __attribute__((ext_vector_type(2)));

__device__ __forceinline__ unsigned short f2bf(float f) {
    union { float f; unsigned u; } v; v.f = f;
    unsigned r = v.u + 0x7fffu + ((v.u >> 16) & 1u);
    return (unsigned short)(r >> 16);
}

// ---------------- deterministic ordered compaction of M --------------------
__global__ void build_gidx(const float* __restrict__ M, int* __restrict__ gidx,
                           int* __restrict__ gcnt) {
    int c = blockIdx.x;
    int t = threadIdx.x;
    __shared__ int wcnt[4];
    __shared__ int base;
    if (t == 0) base = 0;
    __syncthreads();
    for (int g0 = 0; g0 < NG; g0 += 256) {
        int g = g0 + t;
        bool a = (g < NG) && (M[c * NG + g] != 0.0f);
        unsigned long long mask = __ballot(a);
        int lane = t & 63;
        int w = t >> 6;
        if (lane == 0) wcnt[w] = __popcll(mask);
        int pre = __popcll(mask & ((1ull << lane) - 1ull));
        __syncthreads();
        int woff = base;
        for (int i = 0; i < w; ++i) woff += wcnt[i];
        if (a) gidx[c * GS + woff + pre] = g;
        int tot = wcnt[0] + wcnt[1] + wcnt[2] + wcnt[3];
        __syncthreads();
        if (t == 0) base += tot;
        __syncthreads();
    }
    if (t == 0) gcnt[c] = base;
}

// ---------------- prep: X transpose (bf16, gene-major) ---------------------
__global__ void prep_xt(const float* __restrict__ X, unsigned short* __restrict__ xt) {
    __shared__ float tile[64][65];
    int gb = blockIdx.x, bb = blockIdx.y;
    int t = threadIdx.x;
    int tx = t & 63, tq = t >> 6;
    #pragma unroll
    for (int i = 0; i < 16; ++i) {
        int r = tq * 16 + i;
        int gene = gb * 64 + tx;
        tile[r][tx] = (gene < NG) ? X[(size_t)(bb * 64 + r) * NG + gene] : 0.f;
    }
    __syncthreads();
    #pragma unroll
    for (int i = 0; i < 16; ++i) {
        int gl = tq * 16 + i;
        int gene = gb * 64 + gl;
        if (gene < NG)
            xt[(size_t)gene * NB + bb * 64 + tx] = f2bf(tile[tx][gl]);
    }
}

// ---------------- prep: per-concept gathered W1, LDS-ready layout ----------
// w1s[(c*NCH+ch)*256 + col][32] : A-operand (hcol-major rows of 32 k)
__global__ void prep_w1s(const float* __restrict__ W1, const int* __restrict__ gidx,
                         const int* __restrict__ gcnt, unsigned short* __restrict__ w1s) {
    int ch = blockIdx.x, c = blockIdx.y;
    int col = threadIdx.x;
    int cnt = gcnt[c]; if (cnt > KP) cnt = KP;
    unsigned short v[32];
    #pragma unroll
    for (int kin = 0; kin < 32; ++kin) {
        int k = ch * 32 + kin;
        float x = 0.f;
        if (k < cnt) {
            int g = gidx[c * GS + k];
            x = W1[(size_t)g * NH + col];
        }
        v[kin] = f2bf(x);
    }
    unsigned short* dst = w1s + (((size_t)(c * NCH + ch)) * 256 + col) * 32;
    #pragma unroll
    for (int q = 0; q < 4; ++q) {
        short8 v8;
        #pragma unroll
        for (int i = 0; i < 8; ++i) v8[i] = (short)v[q * 8 + i];
        *(short8*)(dst + q * 8) = v8;
    }
}

// ---------------- prep: W2^T chunked, LDS-ready -----------------------------
__global__ void prep_w2s(const float* __restrict__ W2, unsigned short* __restrict__ w2s) {
    int ch = blockIdx.x;           // 8
    int col = threadIdx.x;         // 256
    unsigned short v[32];
    #pragma unroll
    for (int kin = 0; kin < 32; ++kin)
        v[kin] = f2bf(W2[(size_t)(ch * 32 + kin) * NH + col]);
    unsigned short* dst = w2s + ((size_t)ch * 256 + col) * 32;
    #pragma unroll
    for (int q = 0; q < 4; ++q) {
        short8 v8;
        #pragma unroll
        for (int i = 0; i < 8; ++i) v8[i] = (short)v[q * 8 + i];
        *(short8*)(dst + q * 8) = v8;
    }
}

// ---------------- prep: cw bf16, pre-swizzled [o][256] ----------------------
__global__ void prep_cws(const float* __restrict__ cw, unsigned short* __restrict__ cws) {
    int c = blockIdx.x;
    int t = threadIdx.x;
    int o = t >> 3, seg = t & 7;
    #pragma unroll
    for (int blk = 0; blk < 4; ++blk) {
        int k8 = seg * 32 + blk * 8;
        short8 v8;
        #pragma unroll
        for (int i = 0; i < 8; ++i)
            v8[i] = (short)f2bf(cw[((size_t)c * NZD + o) * NH + k8 + i]);
        int db = (k8 >> 3) ^ (o & 7);
        *(short8*)(cws + (size_t)c * 8192 + o * 256 + db * 8) = v8;
    }
}

// ---------------- main fused kernel -----------------------------------------
#define H_BASE   0        // bf16 [64][256] swizzled        (32768 B)
#define SW_BASE  32768    // weights / SCW / protos staging (16384 B)
#define R3_BASE  49152    // stage A: SX [64][32] bf16 (4096) / stage D protos (5960)
#define SZ_BASE  55296    // f32 [64][36]                   ( 9216 B)
#define LDS_BYTES 64512

__global__ __launch_bounds__(512, 4) void fused_mfma2(
    const unsigned short* __restrict__ xt,
    const unsigned short* __restrict__ w1s,
    const unsigned short* __restrict__ w2s,
    const unsigned short* __restrict__ cws,
    const float* __restrict__ b1, const float* __restrict__ b2,
    const float* __restrict__ cb, const float* __restrict__ protos,
    const float* __restrict__ logvar, const float* __restrict__ c_bias,
    const int* __restrict__ gidx, const int* __restrict__ gcnt,
    float* __restrict__ out_cl)
{
    extern __shared__ char sm[];
    const int t  = threadIdx.x;
    const int l  = t & 63;
    const int w  = t >> 6;      // 0..7
    const int lr = l & 15;
    const int lg = l >> 4;      // 0..3
    const int wb = w >> 2;      // 0..1: brow block (32 rows)
    const int wh = w & 3;       // 0..3: hcol block (64 cols)
    const int row0 = blockIdx.x * BT;
    const int c    = blockIdx.y;
    int cnt = gcnt[c]; if (cnt > KP) cnt = KP;
    const int nch = (cnt + 31) >> 5;

    auto Hb = [&](int r, int k) -> char* {
        return sm + H_BASE + r * 512 + ((((k >> 3) ^ (r & 7)) << 4) | ((k & 7) << 1));
    };

    f32x4 acc[2][4];
    #pragma unroll
    for (int nn = 0; nn < 2; ++nn)
        #pragma unroll
        for (int mm = 0; mm < 4; ++mm) acc[nn][mm] = f32x4{0.f, 0.f, 0.f, 0.f};

    // ---------------- stage A: h1 = leaky(Xc @ W1c + b1) --------------------
    const int jj = t & 31, rb = t >> 5;   // SX staging roles
    for (int ch = 0; ch < nch; ++ch) {
        const int kb = ch * 32;
        __syncthreads();
        {   // SW <- w1s (linear 16KB, coalesced, conflict-free)
            const short8* src = (const short8*)(w1s + ((size_t)(c * NCH + ch) * 256) * 32);
            short8 v0 = src[t * 2], v1 = src[t * 2 + 1];
            *(short8*)(sm + SW_BASE + t * 32)      = v0;
            *(short8*)(sm + SW_BASE + t * 32 + 16) = v1;
        }
        {   // SX <- Xt (gene-major 8B loads)
            int g = (kb + jj < cnt) ? gidx[c * GS + kb + jj] : -1;
            short4v xv = short4v{0, 0, 0, 0};
            if (g >= 0) xv = *(const short4v*)(xt + (size_t)g * NB + row0 + rb * 4);
            #pragma unroll
            for (int i = 0; i < 4; ++i)
                *(short*)(sm + R3_BASE + (rb * 4 + i) * 64 + jj * 2) = xv[i];
        }
        __syncthreads();
        short8 a[4], b[2];
        #pragma unroll
        for (int mm = 0; mm < 4; ++mm)
            a[mm] = *(const short8*)(sm + SW_BASE + (wh * 64 + mm * 16 + lr) * 64 + lg * 16);
        #pragma unroll
        for (int nn = 0; nn < 2; ++nn)
            b[nn] = *(const short8*)(sm + R3_BASE + (wb * 32 + nn * 16 + lr) * 64 + lg * 16);
        #pragma unroll
        for (int nn = 0; nn < 2; ++nn)
            #pragma unroll
            for (int mm = 0; mm < 4; ++mm)
                acc[nn][mm] = __builtin_amdgcn_mfma_f32_16x16x32_bf16(a[mm], b[nn], acc[nn][mm], 0, 0, 0);
    }
    // epilogue A: packed b64 writes, D-layout: hcol = lg*4+i, brow = lr
    #pragma unroll
    for (int mm = 0; mm < 4; ++mm) {
        int k0 = wh * 64 + mm * 16 + lg * 4;
        float b1v[4];
        #pragma unroll
        for (int i = 0; i < 4; ++i) b1v[i] = b1[k0 + i];
        #pragma unroll
        for (int nn = 0; nn < 2; ++nn) {
            int r = wb * 32 + nn * 16 + lr;
            unsigned int u0, u1;
            {
                float v0 = acc[nn][mm][0] + b1v[0]; v0 = (v0 >= 0.f) ? v0 : 0.01f * v0;
                float v1 = acc[nn][mm][1] + b1v[1]; v1 = (v1 >= 0.f) ? v1 : 0.01f * v1;
                float v2 = acc[nn][mm][2] + b1v[2]; v2 = (v2 >= 0.f) ? v2 : 0.01f * v2;
                float v3 = acc[nn][mm][3] + b1v[3]; v3 = (v3 >= 0.f) ? v3 : 0.01f * v3;
                u0 = (unsigned)f2bf(v0) | ((unsigned)f2bf(v1) << 16);
                u1 = (unsigned)f2bf(v2) | ((unsigned)f2bf(v3) << 16);
            }
            uint2v p; p[0] = u0; p[1] = u1;
            *(uint2v*)Hb(r, k0) = p;
        }
    }

    // ---------------- stage B: h2 = leaky(h1 @ W2 + b2) ---------------------
    f32x4 acc2[2][4];
    #pragma unroll
    for (int nn = 0; nn < 2; ++nn)
        #pragma unroll
        for (int mm = 0; mm < 4; ++mm) acc2[nn][mm] = f32x4{0.f, 0.f, 0.f, 0.f};

    for (int ch = 0; ch < 8; ++ch) {
        const int kb = ch * 32;
        __syncthreads();
        {   // SW <- w2s
            const short8* src = (const short8*)(w2s + (size_t)ch * 256 * 32);
            short8 v0 = src[t * 2], v1 = src[t * 2 + 1];
            *(short8*)(sm + SW_BASE + t * 32)      = v0;
            *(short8*)(sm + SW_BASE + t * 32 + 16) = v1;
        }
        __syncthreads();
        short8 a[4], b[2];
        #pragma unroll
        for (int mm = 0; mm < 4; ++mm)
            a[mm] = *(const short8*)(sm + SW_BASE + (wh * 64 + mm * 16 + lr) * 64 + lg * 16);
        #pragma unroll
        for (int nn = 0; nn < 2; ++nn)
            b[nn] = *(const short8*)Hb(wb * 32 + nn * 16 + lr, kb + lg * 8);
        #pragma unroll
        for (int nn = 0; nn < 2; ++nn)
            #pragma unroll
            for (int mm = 0; mm < 4; ++mm)
                acc2[nn][mm] = __builtin_amdgcn_mfma_f32_16x16x32_bf16(a[mm], b[nn], acc2[nn][mm], 0, 0, 0);
    }
    __syncthreads();   // all h1 + SW reads complete

    // epilogue B: h2 -> H (overwrite)
    #pragma unroll
    for (int mm = 0; mm < 4; ++mm) {
        int k0 = wh * 64 + mm * 16 + lg * 4;
        float b2v[4];
        #pragma unroll
        for (int i = 0; i < 4; ++i) b2v[i] = b2[k0 + i];
        #pragma unroll
        for (int nn = 0; nn < 2; ++nn) {
            int r = wb * 32 + nn * 16 + lr;
            unsigned int u0, u1;
            {
                float v0 = acc2[nn][mm][0] + b2v[0]; v0 = (v0 >= 0.f) ? v0 : 0.01f * v0;
                float v1 = acc2[nn][mm][1] + b2v[1]; v1 = (v1 >= 0.f) ? v1 : 0.01f * v1;
                float v2 = acc2[nn][mm][2] + b2v[2]; v2 = (v2 >= 0.f) ? v2 : 0.01f * v2;
                float v3 = acc2[nn][mm][3] + b2v[3]; v3 = (v3 >= 0.f) ? v3 : 0.01f * v3;
                u0 = (unsigned)f2bf(v0) | ((unsigned)f2bf(v1) << 16);
                u1 = (unsigned)f2bf(v2) | ((unsigned)f2bf(v3) << 16);
            }
            uint2v p; p[0] = u0; p[1] = u1;
            *(uint2v*)Hb(r, k0) = p;
        }
    }
    {   // stage SCW (pre-swizzled) + protos + i2e + cbias
        const short8* src = (const short8*)(cws + (size_t)c * 8192);
        short8 v0 = src[t * 2], v1 = src[t * 2 + 1];
        *(short8*)(sm + SW_BASE + t * 32)      = v0;
        *(short8*)(sm + SW_BASE + t * 32 + 16) = v1;

        float* pp  = (float*)(sm + R3_BASE);
        for (int i = t; i < NK * NP * NZD; i += 512)
            pp[(i >> 5) * 36 + (i & 31)] = protos[(size_t)c * (NK * NP * NZD) + i];
        float* i2e = (float*)(sm + R3_BASE + 5760);
        if (t < NK * NP) i2e[t] = 0.5f * expf(-logvar[c * (NK * NP) + t]);
        float* cbs = (float*)(sm + R3_BASE + 5920);
        if (t < NK) cbs[t] = c_bias[c * NK + t];
    }
    __syncthreads();

    // ---------------- stage C: Z = h2 @ cw^T + cb (waves 0..3) --------------
    if (w < 4) {
        const int bb = w;
        f32x4 az[2];
        az[0] = f32x4{0.f, 0.f, 0.f, 0.f};
        az[1] = f32x4{0.f, 0.f, 0.f, 0.f};
        for (int ch = 0; ch < 8; ++ch) {
            const int kb = ch * 32;
            short8 b = *(const short8*)Hb(bb * 16 + lr, kb + lg * 8);
            #pragma unroll
            for (int mm = 0; mm < 2; ++mm) {
                int o = mm * 16 + lr;
                short8 a = *(const short8*)(sm + SW_BASE + o * 512 +
                                            ((((kb >> 3) + lg) ^ (o & 7)) << 4));
                az[mm] = __builtin_amdgcn_mfma_f32_16x16x32_bf16(a, b, az[mm], 0, 0, 0);
            }
        }
        float* SZ = (float*)(sm + SZ_BASE);
        #pragma unroll
        for (int mm = 0; mm < 2; ++mm)
            #pragma unroll
            for (int i = 0; i < 4; ++i) {
                int o = mm * 16 + lg * 4 + i;
                SZ[(bb * 16 + lr) * 36 + o] = az[mm][i] + cb[c * NZD + o];
            }
    }
    __syncthreads();

    // ---------------- stage D: prototype distances -> c_logits --------------
    {
        const float* SZ  = (const float*)(sm + SZ_BASE);
        const float* pp  = (const float*)(sm + R3_BASE);
        const float* i2e = (const float*)(sm + R3_BASE + 5760);
        const float* cbs = (const float*)(sm + R3_BASE + 5920);
        const int rloc = (w & 3) * 16 + lr;
        f32x4 z[8];
        #pragma unroll
        for (int j = 0; j < 8; ++j)
            z[j] = *(const f32x4*)(SZ + rloc * 36 + j * 4);
        const int kk0 = (w >> 2) * 5;
        #pragma unroll
        for (int kk = kk0; kk < kk0 + 5; ++kk) {
            int kp = kk * NP + lg;       // lg == p
            f32x4 d = f32x4{0.f, 0.f, 0.f, 0.f};
            #pragma unroll
            for (int j = 0; j < 8; ++j) {
                f32x4 p = *(const f32x4*)(pp + kp * 36 + j * 4);
                f32x4 df = z[j] - p;
                d += df * df;
            }
            float sc = ((d[0] + d[1]) + (d[2] + d[3])) * i2e[kp];
            sc = fminf(sc, __shfl_xor(sc, 16));
            sc = fminf(sc, __shfl_xor(sc, 32));
            if (lg == 0)
                out_cl[((size_t)(row0 + rloc) * NC + c) * NK + kk] = cbs[kk] - sc;
        }
    }
}

// ---------------- fallback (round-1 fp32 path, known-good) -----------------
__global__ __launch_bounds__(256, 1) void fused_main(
    const float* __restrict__ X,  const float* __restrict__ W1,
    const float* __restrict__ b1, const float* __restrict__ W2,
    const float* __restrict__ b2, const float* __restrict__ cw,
    const float* __restrict__ cb, const float* __restrict__ protos,
    const float* __restrict__ logvar, const float* __restrict__ c_bias,
    const int* __restrict__ gidx, const int* __restrict__ gcnt,
    float* __restrict__ out_cl)
{
    extern __shared__ float smemf[];
    float (*sh_big)[258] = (float (*)[258])smemf;
    float (*sh_w)[258]   = (float (*)[258])(smemf + 16512);
    float (*sh_x)[33]    = (float (*)[33])(smemf + 16512 + 8256);
    int*  sh_gid         = (int*)(smemf + 16512 + 8256 + 2112);

    const int t   = threadIdx.x;
    const int tx  = t & 15;
    const int ty  = t >> 4;
    const int row0 = blockIdx.x * BT;
    const int c    = blockIdx.y;

    float acc[4][16];
    #pragma unroll
    for (int i = 0; i < 4; ++i)
        #pragma unroll
        for (int l = 0; l < 16; ++l) acc[i][l] = 0.f;

    const int cnt = gcnt[c];
    const int nch = (cnt + 31) >> 5;
    for (int ch = 0; ch < nch; ++ch) {
        __syncthreads();
        if (t < 32) {
            int gi = ch * 32 + t;
            sh_gid[t] = (gi < cnt) ? gidx[c * GS + gi] : -1;
        }
        __syncthreads();
        #pragma unroll 4
        for (int jj = 0; jj < 32; ++jj) {
            int g = sh_gid[jj];
            sh_w[jj][t] = (g >= 0) ? W1[g * NH + t] : 0.f;
        }
        {
            int j  = t & 31;
            int rb = (t >> 5) * 8;
            int g  = sh_gid[j];
            #pragma unroll
            for (int ii = 0; ii < 8; ++ii)
                sh_x[rb + ii][j] = (g >= 0) ? X[(size_t)(row0 + rb + ii) * NG + g] : 0.f;
        }
        __syncthreads();
        #pragma unroll 8
        for (int j = 0; j < 32; ++j) {
            float xv[4];
            #pragma unroll
            for (int i = 0; i < 4; ++i) xv[i] = sh_x[ty * 4 + i][j];
            #pragma unroll
            for (int l = 0; l < 16; ++l) {
                float wv = sh_w[j][l * 16 + tx];
                #pragma unroll
                for (int i = 0; i < 4; ++i) acc[i][l] = fmaf(xv[i], wv, acc[i][l]);
            }
        }
    }
    #pragma unroll
    for (int i = 0; i < 4; ++i)
        #pragma unroll
        for (int l = 0; l < 16; ++l) {
            int col = l * 16 + tx;
            float v = acc[i][l] + b1[col];
            sh_big[ty * 4 + i][col] = (v >= 0.f) ? v : 0.01f * v;
        }

    float acc2[4][16];
    #pragma unroll
    for (int i = 0; i < 4; ++i)
        #pragma unroll
        for (int l = 0; l < 16; ++l) acc2[i][l] = 0.f;
    for (int ch = 0; ch < NH / 32; ++ch) {
        __syncthreads();
        #pragma unroll 4
        for (int jj = 0; jj < 32; ++jj)
            sh_w[jj][t] = W2[(ch * 32 + jj) * NH + t];
        __syncthreads();
        #pragma unroll 8
        for (int j = 0; j < 32; ++j) {
            float xv[4];
            #pragma unroll
            for (int i = 0; i < 4; ++i) xv[i] = sh_big[ty * 4 + i][ch * 32 + j];
            #pragma unroll
            for (int l = 0; l < 16; ++l) {
                float wv = sh_w[j][l * 16 + tx];
                #pragma unroll
                for (int i = 0; i < 4; ++i) acc2[i][l] = fmaf(xv[i], wv, acc2[i][l]);
            }
        }
    }
    __syncthreads();
    #pragma unroll
    for (int i = 0; i < 4; ++i)
        #pragma unroll
        for (int l = 0; l < 16; ++l) {
            int col = l * 16 + tx;
            float v = acc2[i][l] + b2[col];
            sh_big[ty * 4 + i][col] = (v >= 0.f) ? v : 0.01f * v;
        }
    #pragma unroll 4
    for (int o = 0; o < NZD; ++o)
        sh_w[o][t] = cw[((size_t)c * NZD + o) * NH + t];
    __syncthreads();
    {
        int o  = t & 31;
        int rg = t >> 5;
        float cbv = cb[c * NZD + o];
        float zv[8];
        #pragma unroll
        for (int i = 0; i < 8; ++i) zv[i] = cbv;
        for (int h = 0; h < NH; ++h) {
            float wv = sh_w[o][h];
            #pragma unroll
            for (int i = 0; i < 8; ++i)
                zv[i] = fmaf(sh_big[rg * 8 + i][h], wv, zv[i]);
        }
        #pragma unroll
        for (int i = 0; i < 8; ++i) sh_x[rg * 8 + i][o] = zv[i];
    }
    __syncthreads();
    float* proto_s = &sh_w[0][0];
    float* i2e_s   = proto_s + NK * NP * NZD;
    float* cbias_s = i2e_s + NK * NP;
    for (int i = t; i < NK * NP * NZD; i += 256)
        proto_s[i] = protos[(size_t)c * NK * NP * NZD + i];
    if (t < NK * NP) i2e_s[t] = 0.5f * expf(-logvar[c * NK * NP + t]);
    if (t < NK)      cbias_s[t] = c_bias[c * NK + t];
    __syncthreads();
    for (int task = t; task < BT * NK; task += 256) {
        int r = task / NK;
        int k = task - r * NK;
        float best = 3.4e38f;
        #pragma unroll
        for (int p = 0; p < NP; ++p) {
            float d2 = 0.f;
            const float* ppr = proto_s + (k * NP + p) * NZD;
            #pragma unroll
            for (int o = 0; o < NZD; ++o) {
                float dv = sh_x[r][o] - ppr[o];
                d2 = fmaf(dv, dv, d2);
            }
            float sc = d2 * i2e_s[k * NP + p];
            best = fminf(best, sc);
        }
        out_cl[((size_t)(row0 + r) * NC + c) * NK + k] = cbias_s[k] - best;
    }
}

// ---------------- logits reduce ---------------------------------------------
__global__ void reduce_logits(const float* __restrict__ cl,
                              const float* __restrict__ importance,
                              const float* __restrict__ bias,
                              float* __restrict__ out) {
    int idx = blockIdx.x * blockDim.x + threadIdx.x;
    if (idx >= NB * NK) return;
    int b = idx / NK;
    int k = idx - b * NK;
    float s = 0.f;
    for (int c = 0; c < NC; ++c) {
        float imp = fabsf(importance[c]);
        s += expf(cl[((size_t)b * NC + c) * NK + k]) * imp + 1e-16f;
    }
    out[idx] = logf(s) + bias[k];
}

extern "C" void kernel_launch(void* const* d_in, const int* in_sizes, int n_in,
                              void* d_out, int out_size, void* d_ws, size_t ws_size,
                              hipStream_t stream) {
    const float* X      = (const float*)d_in[0];
    const float* M      = (const float*)d_in[1];
    const float* W1     = (const float*)d_in[2];
    const float* b1     = (const float*)d_in[3];
    const float* W2     = (const float*)d_in[4];
    const float* b2     = (const float*)d_in[5];
    const float* cw     = (const float*)d_in[6];
    const float* cb     = (const float*)d_in[7];
    const float* protos = (const float*)d_in[8];
    const float* logvar = (const float*)d_in[9];
    const float* c_bias = (const float*)d_in[10];
    const float* bias   = (const float*)d_in[11];
    const float* imp    = (const float*)d_in[12];

    float* out_logits = (float*)d_out;
    float* out_cl     = out_logits + NB * NK;

    // workspace layout (bytes)
    const size_t o_gcnt = (size_t)NC * GS * 4;               //  409600
    const size_t o_w1s  = o_gcnt + 256;                      //  409856
    const size_t o_w2s  = o_w1s + (size_t)NC * NCH * 256 * 32 * 2;  // +8192000
    const size_t o_cws  = o_w2s + (size_t)8 * 256 * 32 * 2;         // +131072
    const size_t o_xt   = o_cws + (size_t)NC * 32 * 256 * 2;        // +819200
    const size_t need   = o_xt + (size_t)NG * NB * 2;               // +8192000

    int* gidx = (int*)d_ws;
    int* gcnt = (int*)((char*)d_ws + o_gcnt);
    unsigned short* w1s = (unsigned short*)((char*)d_ws + o_w1s);
    unsigned short* w2s = (unsigned short*)((char*)d_ws + o_w2s);
    unsigned short* cws = (unsigned short*)((char*)d_ws + o_cws);
    unsigned short* xt  = (unsigned short*)((char*)d_ws + o_xt);

    build_gidx<<<NC, 256, 0, stream>>>(M, gidx, gcnt);

    if (ws_size >= need) {
        prep_xt <<<dim3(32, 32), 256, 0, stream>>>(X, xt);
        prep_w1s<<<dim3(NCH, NC), 256, 0, stream>>>(W1, gidx, gcnt, w1s);
        prep_w2s<<<8, 256, 0, stream>>>(W2, w2s);
        prep_cws<<<NC, 256, 0, stream>>>(cw, cws);
        fused_mfma2<<<dim3(NB / BT, NC), 512, LDS_BYTES, stream>>>(
            xt, w1s, w2s, cws, b1, b2, cb, protos, logvar, c_bias, gidx, gcnt, out_cl);
    } else {
        size_t smem = (size_t)(16512 + 8256 + 2112) * 4 + 32 * 4;
        fused_main<<<dim3(NB / BT, NC), 256, smem, stream>>>(
            X, W1, b1, W2, b2, cw, cb, protos, logvar, c_bias, gidx, gcnt, out_cl);
    }
    reduce_logits<<<(NB * NK + 255) / 256, 256, 0, stream>>>(out_cl, imp, bias, out_logits);
}

// Round 4
// 101.520 us; speedup vs baseline: 16.9468x; 1.1753x over previous
//
#include <hip/hip_runtime.h>
#include <hip/hip_bf16.h>

#define NB   2048
#define NG   2000
#define NC   50
#define NH   256
#define NZD  32
#define NK   10
#define NP   4
#define BT   64
#define GS   2048
#define KP   320
#define NCH  10      // KP/32

typedef short short8  __attribute__((ext_vector_type(8)));
typedef short short4v __attribute__((ext_vector_type(4)));
typedef float f32x4   __attribute__((ext_vector_type(4)));
typedef unsigned int uint2v __attribute__((ext_vector_type(2)));

__device__ __forceinline__ unsigned short f2bf(float f) {
    union { float f; unsigned u; } v; v.f = f;
    unsigned r = v.u + 0x7fffu + ((v.u >> 16) & 1u);
    return (unsigned short)(r >> 16);
}

// ---------------- deterministic ordered compaction of M --------------------
__global__ void build_gidx(const float* __restrict__ M, int* __restrict__ gidx,
                           int* __restrict__ gcnt) {
    int c = blockIdx.x;
    int t = threadIdx.x;
    __shared__ int wcnt[4];
    __shared__ int base;
    if (t == 0) base = 0;
    __syncthreads();
    for (int g0 = 0; g0 < NG; g0 += 256) {
        int g = g0 + t;
        bool a = (g < NG) && (M[c * NG + g] != 0.0f);
        unsigned long long mask = __ballot(a);
        int lane = t & 63;
        int w = t >> 6;
        if (lane == 0) wcnt[w] = __popcll(mask);
        int pre = __popcll(mask & ((1ull << lane) - 1ull));
        __syncthreads();
        int woff = base;
        for (int i = 0; i < w; ++i) woff += wcnt[i];
        if (a) gidx[c * GS + woff + pre] = g;
        int tot = wcnt[0] + wcnt[1] + wcnt[2] + wcnt[3];
        __syncthreads();
        if (t == 0) base += tot;
        __syncthreads();
    }
    if (t == 0) gcnt[c] = base;
}

// ---------------- merged prep kernel ---------------------------------------
// blocks [0,1024): X transpose; [1024,1524): w1s; [1524,1532): w2s; [1532,1582): cws
__global__ void prep_all(const float* __restrict__ X, const float* __restrict__ W1,
                         const float* __restrict__ W2, const float* __restrict__ cw,
                         const int* __restrict__ gidx, const int* __restrict__ gcnt,
                         unsigned short* __restrict__ xt, unsigned short* __restrict__ w1s,
                         unsigned short* __restrict__ w2s, unsigned short* __restrict__ cws) {
    __shared__ float tile[64][65];
    const int bx = blockIdx.x;
    const int t  = threadIdx.x;
    if (bx < 1024) {                       // ---- xt: X^T to bf16, gene-major
        int gb = bx & 31, bb = bx >> 5;
        int tx = t & 63, tq = t >> 6;
        #pragma unroll
        for (int i = 0; i < 16; ++i) {
            int r = tq * 16 + i;
            int gene = gb * 64 + tx;
            tile[r][tx] = (gene < NG) ? X[(size_t)(bb * 64 + r) * NG + gene] : 0.f;
        }
        __syncthreads();
        #pragma unroll
        for (int i = 0; i < 16; ++i) {
            int gl = tq * 16 + i;
            int gene = gb * 64 + gl;
            if (gene < NG)
                xt[(size_t)gene * NB + bb * 64 + tx] = f2bf(tile[tx][gl]);
        }
    } else if (bx < 1524) {                // ---- w1s: gathered W1, swizzled
        int idx = bx - 1024;
        int ch = idx % NCH, c = idx / NCH;
        int col = t;
        int cnt = gcnt[c]; if (cnt > KP) cnt = KP;
        unsigned short v[32];
        #pragma unroll
        for (int kin = 0; kin < 32; ++kin) {
            int k = ch * 32 + kin;
            float x = 0.f;
            if (k < cnt) {
                int g = gidx[c * GS + k];
                x = W1[(size_t)g * NH + col];
            }
            v[kin] = f2bf(x);
        }
        unsigned short* dst = w1s + (((size_t)(c * NCH + ch)) * 256 + col) * 32;
        #pragma unroll
        for (int q = 0; q < 4; ++q) {
            short8 v8;
            #pragma unroll
            for (int i = 0; i < 8; ++i) v8[i] = (short)v[q * 8 + i];
            *(short8*)(dst + (q ^ (col & 3)) * 8) = v8;
        }
    } else if (bx < 1532) {                // ---- w2s: W2^T chunks, swizzled
        int ch = bx - 1524;
        int col = t;
        unsigned short v[32];
        #pragma unroll
        for (int kin = 0; kin < 32; ++kin)
            v[kin] = f2bf(W2[(size_t)(ch * 32 + kin) * NH + col]);
        unsigned short* dst = w2s + ((size_t)ch * 256 + col) * 32;
        #pragma unroll
        for (int q = 0; q < 4; ++q) {
            short8 v8;
            #pragma unroll
            for (int i = 0; i < 8; ++i) v8[i] = (short)v[q * 8 + i];
            *(short8*)(dst + (q ^ (col & 3)) * 8) = v8;
        }
    } else {                               // ---- cws: cw bf16, pre-swizzled
        int c = bx - 1532;
        int o = t >> 3, seg = t & 7;
        #pragma unroll
        for (int blk = 0; blk < 4; ++blk) {
            int k8 = seg * 32 + blk * 8;
            short8 v8;
            #pragma unroll
            for (int i = 0; i < 8; ++i)
                v8[i] = (short)f2bf(cw[((size_t)c * NZD + o) * NH + k8 + i]);
            int db = (k8 >> 3) ^ (o & 7);
            *(short8*)(cws + (size_t)c * 8192 + o * 256 + db * 8) = v8;
        }
    }
}

// ---------------- main fused kernel -----------------------------------------
#define H_BASE   0        // bf16 [64][256] swizzled (32768 B)
#define SWA      32768    // 16 KB staging buf A (later: SCW)
#define SWB      49152    // 16 KB staging buf B (later: SZ f32 [64][36])
#define SXA      65536    // 4 KB X buf A  (later: protos 5960 B spans SXA+SXB)
#define SXB      69632    // 4 KB X buf B
#define LDS_BYTES 73728

__global__ __launch_bounds__(512, 4) void fused_mfma3(
    const unsigned short* __restrict__ xt,
    const unsigned short* __restrict__ w1s,
    const unsigned short* __restrict__ w2s,
    const unsigned short* __restrict__ cws,
    const float* __restrict__ b1, const float* __restrict__ b2,
    const float* __restrict__ cb, const float* __restrict__ protos,
    const float* __restrict__ logvar, const float* __restrict__ c_bias,
    const int* __restrict__ gidx, const int* __restrict__ gcnt,
    float* __restrict__ out_cl)
{
    extern __shared__ char sm[];
    const int t  = threadIdx.x;
    const int l  = t & 63;
    const int w  = t >> 6;      // 0..7
    const int lr = l & 15;
    const int lg = l >> 4;      // 0..3
    const int wb = w >> 2;      // 0..1: row block (32 rows)
    const int wh = w & 3;       // 0..3: col block (64 cols)
    const int row0 = blockIdx.x * BT;
    const int c    = blockIdx.y;
    int cnt = gcnt[c]; if (cnt > KP) cnt = KP;
    const int nch = (cnt + 31) >> 5;

    auto Hb = [&](int r, int k) -> char* {
        return sm + H_BASE + r * 512 + ((((k >> 3) ^ (r & 7)) << 4) | ((k & 7) << 1));
    };

    const int jj = t & 31, rb = t >> 5;   // X staging roles: gene jj, row-block rb

    auto load_w = [&](const unsigned short* src, short8& v0, short8& v1) {
        v0 = *(const short8*)(src + t * 16);
        v1 = *(const short8*)(src + t * 16 + 8);
    };
    auto write_w = [&](int base, short8 v0, short8 v1) {
        *(short8*)(sm + base + t * 32)      = v0;
        *(short8*)(sm + base + t * 32 + 16) = v1;
    };
    auto load_x = [&](int kb, short4v& xv) {
        int g = (kb + jj < cnt) ? gidx[c * GS + kb + jj] : -1;
        xv = short4v{0, 0, 0, 0};
        if (g >= 0) xv = *(const short4v*)(xt + (size_t)g * NB + row0 + rb * 4);
    };
    auto write_x = [&](int base, short4v xv) {
        #pragma unroll
        for (int i = 0; i < 4; ++i) {
            int r = rb * 4 + i;
            *(short*)(sm + base + r * 64 + ((((jj >> 3) ^ (r & 3)) << 4) | ((jj & 7) << 1))) = xv[i];
        }
    };

    f32x4 acc[2][4];
    #pragma unroll
    for (int nn = 0; nn < 2; ++nn)
        #pragma unroll
        for (int mm = 0; mm < 4; ++mm) acc[nn][mm] = f32x4{0.f, 0.f, 0.f, 0.f};

    // ---------------- stage A: h1 = leaky(Xc @ W1c + b1), double-buffered ---
    {
        short8 wv0, wv1; short4v xv;
        load_w(w1s + (size_t)c * NCH * 8192, wv0, wv1);
        load_x(0, xv);
        write_w(SWA, wv0, wv1);
        write_x(SXA, xv);
        __syncthreads();
        for (int ch = 0; ch < nch; ++ch) {
            const int p = ch & 1;
            const int swp = p ? SWB : SWA;
            const int sxp = p ? SXB : SXA;
            const bool haveA = (ch + 1 < nch);
            short8 nw0, nw1; short4v nxv;
            if (haveA) {
                load_w(w1s + (size_t)(c * NCH + ch + 1) * 8192, nw0, nw1);
                load_x((ch + 1) * 32, nxv);
            } else {
                load_w(w2s, nw0, nw1);      // prefetch B-chunk 0
            }
            short8 a[4], b[2];
            #pragma unroll
            for (int mm = 0; mm < 4; ++mm) {
                int col = wh * 64 + mm * 16 + lr;
                a[mm] = *(const short8*)(sm + swp + col * 64 + ((lg ^ (col & 3)) << 4));
            }
            #pragma unroll
            for (int nn = 0; nn < 2; ++nn) {
                int r = wb * 32 + nn * 16 + lr;
                b[nn] = *(const short8*)(sm + sxp + r * 64 + ((lg ^ (r & 3)) << 4));
            }
            #pragma unroll
            for (int nn = 0; nn < 2; ++nn)
                #pragma unroll
                for (int mm = 0; mm < 4; ++mm)
                    acc[nn][mm] = __builtin_amdgcn_mfma_f32_16x16x32_bf16(a[mm], b[nn], acc[nn][mm], 0, 0, 0);
            write_w(p ? SWA : SWB, nw0, nw1);
            if (haveA) write_x(p ? SXA : SXB, nxv);
            __syncthreads();
        }
    }
    // epilogue A: bias + leaky -> H (bf16 packed writes)
    #pragma unroll
    for (int mm = 0; mm < 4; ++mm) {
        int k0 = wh * 64 + mm * 16 + lg * 4;
        f32x4 b1v = *(const f32x4*)(b1 + k0);
        #pragma unroll
        for (int nn = 0; nn < 2; ++nn) {
            int r = wb * 32 + nn * 16 + lr;
            float v0 = acc[nn][mm][0] + b1v[0]; v0 = (v0 >= 0.f) ? v0 : 0.01f * v0;
            float v1 = acc[nn][mm][1] + b1v[1]; v1 = (v1 >= 0.f) ? v1 : 0.01f * v1;
            float v2 = acc[nn][mm][2] + b1v[2]; v2 = (v2 >= 0.f) ? v2 : 0.01f * v2;
            float v3 = acc[nn][mm][3] + b1v[3]; v3 = (v3 >= 0.f) ? v3 : 0.01f * v3;
            uint2v pk;
            pk[0] = (unsigned)f2bf(v0) | ((unsigned)f2bf(v1) << 16);
            pk[1] = (unsigned)f2bf(v2) | ((unsigned)f2bf(v3) << 16);
            *(uint2v*)Hb(r, k0) = pk;
        }
    }
    __syncthreads();

    // ---------------- stage B: h2 = leaky(h1 @ W2 + b2), double-buffered ----
    f32x4 acc2[2][4];
    #pragma unroll
    for (int nn = 0; nn < 2; ++nn)
        #pragma unroll
        for (int mm = 0; mm < 4; ++mm) acc2[nn][mm] = f32x4{0.f, 0.f, 0.f, 0.f};
    for (int ch = 0; ch < 8; ++ch) {
        const int p = (nch + ch) & 1;
        const int swp = p ? SWB : SWA;
        const bool haveB = (ch + 1 < 8);
        short8 nw0, nw1;
        if (haveB) load_w(w2s + (size_t)(ch + 1) * 8192, nw0, nw1);
        short8 a[4], b[2];
        #pragma unroll
        for (int mm = 0; mm < 4; ++mm) {
            int col = wh * 64 + mm * 16 + lr;
            a[mm] = *(const short8*)(sm + swp + col * 64 + ((lg ^ (col & 3)) << 4));
        }
        #pragma unroll
        for (int nn = 0; nn < 2; ++nn)
            b[nn] = *(const short8*)Hb(wb * 32 + nn * 16 + lr, ch * 32 + lg * 8);
        #pragma unroll
        for (int nn = 0; nn < 2; ++nn)
            #pragma unroll
            for (int mm = 0; mm < 4; ++mm)
                acc2[nn][mm] = __builtin_amdgcn_mfma_f32_16x16x32_bf16(a[mm], b[nn], acc2[nn][mm], 0, 0, 0);
        if (haveB) write_w(p ? SWA : SWB, nw0, nw1);
        __syncthreads();
    }

    // epilogue B + stage SCW/protos (loads issued first to hide latency)
    {
        short8 s0 = *(const short8*)(cws + (size_t)c * 8192 + t * 16);
        short8 s1 = *(const short8*)(cws + (size_t)c * 8192 + t * 16 + 8);
        #pragma unroll
        for (int mm = 0; mm < 4; ++mm) {
            int k0 = wh * 64 + mm * 16 + lg * 4;
            f32x4 b2v = *(const f32x4*)(b2 + k0);
            #pragma unroll
            for (int nn = 0; nn < 2; ++nn) {
                int r = wb * 32 + nn * 16 + lr;
                float v0 = acc2[nn][mm][0] + b2v[0]; v0 = (v0 >= 0.f) ? v0 : 0.01f * v0;
                float v1 = acc2[nn][mm][1] + b2v[1]; v1 = (v1 >= 0.f) ? v1 : 0.01f * v1;
                float v2 = acc2[nn][mm][2] + b2v[2]; v2 = (v2 >= 0.f) ? v2 : 0.01f * v2;
                float v3 = acc2[nn][mm][3] + b2v[3]; v3 = (v3 >= 0.f) ? v3 : 0.01f * v3;
                uint2v pk;
                pk[0] = (unsigned)f2bf(v0) | ((unsigned)f2bf(v1) << 16);
                pk[1] = (unsigned)f2bf(v2) | ((unsigned)f2bf(v3) << 16);
                *(uint2v*)Hb(r, k0) = pk;
            }
        }
        write_w(SWA, s0, s1);               // SCW -> SWA (both bufs dead now)
        float* pp = (float*)(sm + SXA);     // protos [40][36] f32 (spans SXA+SXB)
        for (int i = t; i < NK * NP * NZD; i += 512)
            pp[(i >> 5) * 36 + (i & 31)] = protos[(size_t)c * (NK * NP * NZD) + i];
        if (t < NK * NP) pp[1440 + t] = 0.5f * expf(-logvar[c * (NK * NP) + t]);
        if (t < NK)      pp[1480 + t] = c_bias[c * NK + t];
    }
    __syncthreads();

    // ---------------- stage C: Z = h2 @ cw^T + cb (all 8 waves) -------------
    {
        const int rt = w & 3, ot = w >> 2;
        f32x4 az = f32x4{0.f, 0.f, 0.f, 0.f};
        const int o = ot * 16 + lr;
        for (int ch = 0; ch < 8; ++ch) {
            const int kb = ch * 32;
            short8 bfr = *(const short8*)Hb(rt * 16 + lr, kb + lg * 8);
            short8 afr = *(const short8*)(sm + SWA + o * 512 +
                                          ((((kb >> 3) + lg) ^ (o & 7)) << 4));
            az = __builtin_amdgcn_mfma_f32_16x16x32_bf16(afr, bfr, az, 0, 0, 0);
        }
        f32x4 cb4 = *(const f32x4*)(cb + c * NZD + ot * 16 + lg * 4);
        float* SZ = (float*)(sm + SWB);
        #pragma unroll
        for (int i = 0; i < 4; ++i)
            SZ[(rt * 16 + lr) * 36 + ot * 16 + lg * 4 + i] = az[i] + cb4[i];
    }
    __syncthreads();

    // ---------------- stage D: prototype distances -> c_logits --------------
    {
        const float* SZ  = (const float*)(sm + SWB);
        const float* pp  = (const float*)(sm + SXA);
        const float* i2e = pp + 1440;
        const float* cbs = pp + 1480;
        const int rloc = (w & 3) * 16 + lr;
        f32x4 z[8];
        #pragma unroll
        for (int j = 0; j < 8; ++j)
            z[j] = *(const f32x4*)(SZ + rloc * 36 + j * 4);
        const int kk0 = (w >> 2) * 5;
        #pragma unroll
        for (int kk = kk0; kk < kk0 + 5; ++kk) {
            int kp = kk * NP + lg;       // lg == p
            f32x4 d = f32x4{0.f, 0.f, 0.f, 0.f};
            #pragma unroll
            for (int j = 0; j < 8; ++j) {
                f32x4 p = *(const f32x4*)(pp + kp * 36 + j * 4);
                f32x4 df = z[j] - p;
                d += df * df;
            }
            float sc = ((d[0] + d[1]) + (d[2] + d[3])) * i2e[kp];
            sc = fminf(sc, __shfl_xor(sc, 16));
            sc = fminf(sc, __shfl_xor(sc, 32));
            if (lg == 0)
                out_cl[((size_t)(row0 + rloc) * NC + c) * NK + kk] = cbs[kk] - sc;
        }
    }
}

// ---------------- fallback (round-1 fp32 path, known-good) -----------------
__global__ __launch_bounds__(256, 1) void fused_main(
    const float* __restrict__ X,  const float* __restrict__ W1,
    const float* __restrict__ b1, const float* __restrict__ W2,
    const float* __restrict__ b2, const float* __restrict__ cw,
    const float* __restrict__ cb, const float* __restrict__ protos,
    const float* __restrict__ logvar, const float* __restrict__ c_bias,
    const int* __restrict__ gidx, const int* __restrict__ gcnt,
    float* __restrict__ out_cl)
{
    extern __shared__ float smemf[];
    float (*sh_big)[258] = (float (*)[258])smemf;
    float (*sh_w)[258]   = (float (*)[258])(smemf + 16512);
    float (*sh_x)[33]    = (float (*)[33])(smemf + 16512 + 8256);
    int*  sh_gid         = (int*)(smemf + 16512 + 8256 + 2112);

    const int t   = threadIdx.x;
    const int tx  = t & 15;
    const int ty  = t >> 4;
    const int row0 = blockIdx.x * BT;
    const int c    = blockIdx.y;

    float acc[4][16];
    #pragma unroll
    for (int i = 0; i < 4; ++i)
        #pragma unroll
        for (int l = 0; l < 16; ++l) acc[i][l] = 0.f;

    const int cnt = gcnt[c];
    const int nch = (cnt + 31) >> 5;
    for (int ch = 0; ch < nch; ++ch) {
        __syncthreads();
        if (t < 32) {
            int gi = ch * 32 + t;
            sh_gid[t] = (gi < cnt) ? gidx[c * GS + gi] : -1;
        }
        __syncthreads();
        #pragma unroll 4
        for (int jj = 0; jj < 32; ++jj) {
            int g = sh_gid[jj];
            sh_w[jj][t] = (g >= 0) ? W1[g * NH + t] : 0.f;
        }
        {
            int j  = t & 31;
            int rb2 = (t >> 5) * 8;
            int g  = sh_gid[j];
            #pragma unroll
            for (int ii = 0; ii < 8; ++ii)
                sh_x[rb2 + ii][j] = (g >= 0) ? X[(size_t)(row0 + rb2 + ii) * NG + g] : 0.f;
        }
        __syncthreads();
        #pragma unroll 8
        for (int j = 0; j < 32; ++j) {
            float xv[4];
            #pragma unroll
            for (int i = 0; i < 4; ++i) xv[i] = sh_x[ty * 4 + i][j];
            #pragma unroll
            for (int l = 0; l < 16; ++l) {
                float wv = sh_w[j][l * 16 + tx];
                #pragma unroll
                for (int i = 0; i < 4; ++i) acc[i][l] = fmaf(xv[i], wv, acc[i][l]);
            }
        }
    }
    #pragma unroll
    for (int i = 0; i < 4; ++i)
        #pragma unroll
        for (int l = 0; l < 16; ++l) {
            int col = l * 16 + tx;
            float v = acc[i][l] + b1[col];
            sh_big[ty * 4 + i][col] = (v >= 0.f) ? v : 0.01f * v;
        }

    float acc2[4][16];
    #pragma unroll
    for (int i = 0; i < 4; ++i)
        #pragma unroll
        for (int l = 0; l < 16; ++l) acc2[i][l] = 0.f;
    for (int ch = 0; ch < NH / 32; ++ch) {
        __syncthreads();
        #pragma unroll 4
        for (int jj = 0; jj < 32; ++jj)
            sh_w[jj][t] = W2[(size_t)(ch * 32 + jj) * NH + t];
        __syncthreads();
        #pragma unroll 8
        for (int j = 0; j < 32; ++j) {
            float xv[4];
            #pragma unroll
            for (int i = 0; i < 4; ++i) xv[i] = sh_big[ty * 4 + i][ch * 32 + j];
            #pragma unroll
            for (int l = 0; l < 16; ++l) {
                float wv = sh_w[j][l * 16 + tx];
                #pragma unroll
                for (int i = 0; i < 4; ++i) acc2[i][l] = fmaf(xv[i], wv, acc2[i][l]);
            }
        }
    }
    __syncthreads();
    #pragma unroll
    for (int i = 0; i < 4; ++i)
        #pragma unroll
        for (int l = 0; l < 16; ++l) {
            int col = l * 16 + tx;
            float v = acc2[i][l] + b2[col];
            sh_big[ty * 4 + i][col] = (v >= 0.f) ? v : 0.01f * v;
        }
    #pragma unroll 4
    for (int o = 0; o < NZD; ++o)
        sh_w[o][t] = cw[((size_t)c * NZD + o) * NH + t];
    __syncthreads();
    {
        int o  = t & 31;
        int rg = t >> 5;
        float cbv = cb[c * NZD + o];
        float zv[8];
        #pragma unroll
        for (int i = 0; i < 8; ++i) zv[i] = cbv;
        for (int h = 0; h < NH; ++h) {
            float wv = sh_w[o][h];
            #pragma unroll
            for (int i = 0; i < 8; ++i)
                zv[i] = fmaf(sh_big[rg * 8 + i][h], wv, zv[i]);
        }
        #pragma unroll
        for (int i = 0; i < 8; ++i) sh_x[rg * 8 + i][o] = zv[i];
    }
    __syncthreads();
    float* proto_s = &sh_w[0][0];
    float* i2e_s   = proto_s + NK * NP * NZD;
    float* cbias_s = i2e_s + NK * NP;
    for (int i = t; i < NK * NP * NZD; i += 256)
        proto_s[i] = protos[(size_t)c * NK * NP * NZD + i];
    if (t < NK * NP) i2e_s[t] = 0.5f * expf(-logvar[c * NK * NP + t]);
    if (t < NK)      cbias_s[t] = c_bias[c * NK + t];
    __syncthreads();
    for (int task = t; task < BT * NK; task += 256) {
        int r = task / NK;
        int k = task - r * NK;
        float best = 3.4e38f;
        #pragma unroll
        for (int p = 0; p < NP; ++p) {
            float d2 = 0.f;
            const float* ppr = proto_s + (k * NP + p) * NZD;
            #pragma unroll
            for (int o = 0; o < NZD; ++o) {
                float dv = sh_x[r][o] - ppr[o];
                d2 = fmaf(dv, dv, d2);
            }
            float sc = d2 * i2e_s[k * NP + p];
            best = fminf(best, sc);
        }
        out_cl[((size_t)(row0 + r) * NC + c) * NK + k] = cbias_s[k] - best;
    }
}

// ---------------- logits reduce ---------------------------------------------
__global__ void reduce_logits(const float* __restrict__ cl,
                              const float* __restrict__ importance,
                              const float* __restrict__ bias,
                              float* __restrict__ out) {
    int idx = blockIdx.x * blockDim.x + threadIdx.x;
    if (idx >= NB * NK) return;
    int b = idx / NK;
    int k = idx - b * NK;
    float s = 0.f;
    for (int c = 0; c < NC; ++c) {
        float imp = fabsf(importance[c]);
        s += expf(cl[((size_t)b * NC + c) * NK + k]) * imp + 1e-16f;
    }
    out[idx] = logf(s) + bias[k];
}

extern "C" void kernel_launch(void* const* d_in, const int* in_sizes, int n_in,
                              void* d_out, int out_size, void* d_ws, size_t ws_size,
                              hipStream_t stream) {
    const float* X      = (const float*)d_in[0];
    const float* M      = (const float*)d_in[1];
    const float* W1     = (const float*)d_in[2];
    const float* b1     = (const float*)d_in[3];
    const float* W2     = (const float*)d_in[4];
    const float* b2     = (const float*)d_in[5];
    const float* cw     = (const float*)d_in[6];
    const float* cb     = (const float*)d_in[7];
    const float* protos = (const float*)d_in[8];
    const float* logvar = (const float*)d_in[9];
    const float* c_bias = (const float*)d_in[10];
    const float* bias   = (const float*)d_in[11];
    const float* imp    = (const float*)d_in[12];

    float* out_logits = (float*)d_out;
    float* out_cl     = out_logits + NB * NK;

    // workspace layout (bytes)
    const size_t o_gcnt = (size_t)NC * GS * 4;
    const size_t o_w1s  = o_gcnt + 256;
    const size_t o_w2s  = o_w1s + (size_t)NC * NCH * 256 * 32 * 2;
    const size_t o_cws  = o_w2s + (size_t)8 * 256 * 32 * 2;
    const size_t o_xt   = o_cws + (size_t)NC * 32 * 256 * 2;
    const size_t need   = o_xt + (size_t)NG * NB * 2;

    int* gidx = (int*)d_ws;
    int* gcnt = (int*)((char*)d_ws + o_gcnt);
    unsigned short* w1s = (unsigned short*)((char*)d_ws + o_w1s);
    unsigned short* w2s = (unsigned short*)((char*)d_ws + o_w2s);
    unsigned short* cws = (unsigned short*)((char*)d_ws + o_cws);
    unsigned short* xt  = (unsigned short*)((char*)d_ws + o_xt);

    build_gidx<<<NC, 256, 0, stream>>>(M, gidx, gcnt);

    if (ws_size >= need) {
        prep_all<<<1582, 256, 0, stream>>>(X, W1, W2, cw, gidx, gcnt, xt, w1s, w2s, cws);
        fused_mfma3<<<dim3(NB / BT, NC), 512, LDS_BYTES, stream>>>(
            xt, w1s, w2s, cws, b1, b2, cb, protos, logvar, c_bias, gidx, gcnt, out_cl);
    } else {
        size_t smem = (size_t)(16512 + 8256 + 2112) * 4 + 32 * 4;
        fused_main<<<dim3(NB / BT, NC), 256, smem, stream>>>(
            X, W1, b1, W2, b2, cw, cb, protos, logvar, c_bias, gidx, gcnt, out_cl);
    }
    reduce_logits<<<(NB * NK + 255) / 256, 256, 0, stream>>>(out_cl, imp, bias, out_logits);
}